// Round 1
// baseline (904.997 us; speedup 1.0000x reference)
//
#include <hip/hip_runtime.h>
#include <math.h>

// GAT 2-layer forward on MI355X.
// Structure: CSR build (count/scan/scatter) once per call, then per layer:
//   gemm_alpha: h = x@W, alpha_s/d = per-head dot(h, a)   (wave-per-row fp32)
//   aggregate:  wave-per-dst-node segment softmax + weighted sum, fused epilogue.

constexpr int FDIM = 64;

// ---------------- CSR build ----------------

__global__ void count_kernel(const int* __restrict__ ei, int E, int Etot,
                             int* __restrict__ cnt) {
  int i = blockIdx.x * blockDim.x + threadIdx.x;
  int stride = gridDim.x * blockDim.x;
  for (; i < Etot; i += stride) {
    int dst = (i < E) ? ei[E + i] : (i - E);   // self-loops appended
    atomicAdd(&cnt[dst], 1);
  }
}

__global__ __launch_bounds__(1024) void scan_kernel(
    const int* __restrict__ cnt, int N, int Etot,
    int* __restrict__ row_start, int* __restrict__ cursor) {
  __shared__ int lds[1024];
  int t = threadIdx.x;
  int chunk = (N + 1023) / 1024;
  int lo = t * chunk;
  int hi = min(N, lo + chunk);
  int s = 0;
  for (int i = lo; i < hi; ++i) s += cnt[i];
  lds[t] = s;
  __syncthreads();
  for (int off = 1; off < 1024; off <<= 1) {
    int v = (t >= off) ? lds[t - off] : 0;
    __syncthreads();
    lds[t] += v;
    __syncthreads();
  }
  int run = lds[t] - s;  // exclusive prefix of this thread's chunk
  for (int i = lo; i < hi; ++i) {
    row_start[i] = run;
    cursor[i] = run;
    run += cnt[i];
  }
  if (t == 1023) row_start[N] = Etot;
}

__global__ void scatter_kernel(const int* __restrict__ ei, int E, int Etot,
                               int* __restrict__ cursor, int* __restrict__ esrc) {
  int i = blockIdx.x * blockDim.x + threadIdx.x;
  int stride = gridDim.x * blockDim.x;
  for (; i < Etot; i += stride) {
    int src, dst;
    if (i < E) { src = ei[i]; dst = ei[E + i]; }
    else       { src = i - E; dst = i - E; }
    int pos = atomicAdd(&cursor[dst], 1);
    esrc[pos] = src;
  }
}

// ---------------- GEMM (x @ W) + attention logits ----------------
// One wave per row. W staged in LDS. h[n][o] = sum_k x[n][k] * W[k][o].
// alpha_s[n][head] = sum_c h[n][head*G'..] * a_s  (reduce within 64/HEADS lanes)

template <int HEADS>
__global__ __launch_bounds__(256) void gemm_alpha_kernel(
    const float* __restrict__ X, const float* __restrict__ W,
    const float* __restrict__ a_s, const float* __restrict__ a_d, int N,
    float* __restrict__ H, float* __restrict__ AS, float* __restrict__ AD) {
  __shared__ float Ws[FDIM * FDIM];
  for (int i = threadIdx.x; i < FDIM * FDIM; i += 256) Ws[i] = W[i];
  __syncthreads();

  int lane = threadIdx.x & 63;
  int wid = threadIdx.x >> 6;
  constexpr int G = 64 / HEADS;  // lanes per head group
  float as_l = a_s[lane];
  float ad_l = a_d[lane];

  int n = blockIdx.x * 4 + wid;
  if (n >= N) return;

  float xr = X[(size_t)n * FDIM + lane];
  float acc = 0.f;
#pragma unroll
  for (int k = 0; k < FDIM; ++k) {
    float xv = __shfl(xr, k, 64);
    acc = fmaf(xv, Ws[k * FDIM + lane], acc);
  }
  H[(size_t)n * FDIM + lane] = acc;

  float ts = acc * as_l;
  float td = acc * ad_l;
#pragma unroll
  for (int off = 1; off < G; off <<= 1) {
    ts += __shfl_xor(ts, off, 64);
    td += __shfl_xor(td, off, 64);
  }
  if ((lane & (G - 1)) == 0) {
    int head = lane / G;
    AS[(size_t)n * HEADS + head] = ts;
    AD[(size_t)n * HEADS + head] = td;
  }
}

// ---------------- segment softmax + weighted aggregation ----------------
// One wave per destination node; lane = output channel; head = lane/(64/HEADS).
// Pass 1: per-head max of leaky(e). Pass 2: exp-sum + weighted feature sum.
// FINAL=false: fuse +bias, ELU.  FINAL=true: fuse +bias, row L2-normalize.

template <int HEADS, bool FINAL>
__global__ __launch_bounds__(256) void aggregate_kernel(
    const int* __restrict__ row_start, const int* __restrict__ esrc,
    const float* __restrict__ H, const float* __restrict__ AS,
    const float* __restrict__ AD, const float* __restrict__ bias, int N,
    float* __restrict__ OUT) {
  int lane = threadIdx.x & 63;
  int wid = threadIdx.x >> 6;
  int n = blockIdx.x * 4 + wid;
  if (n >= N) return;

  constexpr int G = 64 / HEADS;
  int head = lane / G;

  int rs = row_start[n];
  int re = row_start[n + 1];
  float ad = AD[(size_t)n * HEADS + head];

  float m = -1e30f;
  for (int i = rs; i < re; ++i) {
    int s = esrc[i];
    float e = AS[(size_t)s * HEADS + head] + ad;
    e = e > 0.f ? e : 0.2f * e;
    m = fmaxf(m, e);
  }

  float denom = 0.f;
  float acc = 0.f;
  for (int i = rs; i < re; ++i) {
    int s = esrc[i];
    float e = AS[(size_t)s * HEADS + head] + ad;
    e = e > 0.f ? e : 0.2f * e;
    float w = __expf(e - m);
    denom += w;
    acc = fmaf(w, H[(size_t)s * FDIM + lane], acc);
  }

  float v = acc / (denom + 1e-16f) + bias[lane];
  if (FINAL) {
    float ss = v * v;
#pragma unroll
    for (int off = 1; off < 64; off <<= 1) ss += __shfl_xor(ss, off, 64);
    float norm = fmaxf(sqrtf(ss), 1e-12f);
    OUT[(size_t)n * FDIM + lane] = v / norm;
  } else {
    OUT[(size_t)n * FDIM + lane] = v > 0.f ? v : expm1f(v);
  }
}

// ---------------- launch ----------------

extern "C" void kernel_launch(void* const* d_in, const int* in_sizes, int n_in,
                              void* d_out, int out_size, void* d_ws,
                              size_t ws_size, hipStream_t stream) {
  const int* ei = (const int*)d_in[0];          // [2, E] (src row, dst row)
  const float* emb = (const float*)d_in[1];     // [N, 64]
  const float* W1 = (const float*)d_in[2];      // [64, 64]
  const float* as1 = (const float*)d_in[3];     // [4, 16] flat = 64
  const float* ad1 = (const float*)d_in[4];
  const float* b1 = (const float*)d_in[5];      // [64]
  const float* W2 = (const float*)d_in[6];      // [64, 64]
  const float* as2 = (const float*)d_in[7];     // [1, 64]
  const float* ad2 = (const float*)d_in[8];
  const float* b2 = (const float*)d_in[9];      // [64]
  float* out = (float*)d_out;

  int E = in_sizes[0] / 2;
  int N = in_sizes[1] / FDIM;
  int Etot = E + N;

  char* ws = (char*)d_ws;
  size_t off = 0;
  auto alloc = [&](size_t bytes) -> void* {
    void* p = ws + off;
    off += (bytes + 255) & ~(size_t)255;
    return p;
  };
  int* cnt = (int*)alloc((size_t)N * sizeof(int));
  int* row_start = (int*)alloc((size_t)(N + 1) * sizeof(int));
  int* cursor = (int*)alloc((size_t)N * sizeof(int));
  int* esrc = (int*)alloc((size_t)Etot * sizeof(int));
  float* hbuf = (float*)alloc((size_t)N * FDIM * sizeof(float));
  float* xbuf = (float*)alloc((size_t)N * FDIM * sizeof(float));
  float* AS = (float*)alloc((size_t)N * 4 * sizeof(float));
  float* AD = (float*)alloc((size_t)N * 4 * sizeof(float));

  hipMemsetAsync(cnt, 0, (size_t)N * sizeof(int), stream);
  count_kernel<<<1024, 256, 0, stream>>>(ei, E, Etot, cnt);
  scan_kernel<<<1, 1024, 0, stream>>>(cnt, N, Etot, row_start, cursor);
  scatter_kernel<<<1024, 256, 0, stream>>>(ei, E, Etot, cursor, esrc);

  int gb = (N + 3) / 4;
  // Layer 1: GATConv(64 -> 16, heads=4, concat) + bias + ELU
  gemm_alpha_kernel<4><<<gb, 256, 0, stream>>>(emb, W1, as1, ad1, N, hbuf, AS, AD);
  aggregate_kernel<4, false><<<gb, 256, 0, stream>>>(row_start, esrc, hbuf, AS, AD, b1, N, xbuf);
  // Layer 2: GATConv(64 -> 64, heads=1) + bias + L2 normalize
  gemm_alpha_kernel<1><<<gb, 256, 0, stream>>>(xbuf, W2, as2, ad2, N, hbuf, AS, AD);
  aggregate_kernel<1, true><<<gb, 256, 0, stream>>>(row_start, esrc, hbuf, AS, AD, b2, N, out);
}

// Round 2
// 534.442 us; speedup vs baseline: 1.6933x; 1.6933x over previous
//
#include <hip/hip_runtime.h>
#include <math.h>

// GAT 2-layer forward on MI355X.
// CSR build (count / 3-phase parallel scan / scatter) once per call, then per layer:
//   gemm_alpha: h = x@W (W column in VGPRs, shfl-broadcast x), attention logits
//   aggregate:  wave-per-dst-node ONLINE-softmax weighted sum, fused epilogue.

constexpr int FDIM = 64;

// ---------------- CSR build ----------------

__global__ void count_kernel(const int* __restrict__ ei, int E, int Etot,
                             int* __restrict__ cnt) {
  int i = blockIdx.x * blockDim.x + threadIdx.x;
  int stride = gridDim.x * blockDim.x;
  for (; i < Etot; i += stride) {
    int dst = (i < E) ? ei[E + i] : (i - E);   // self-loops appended
    atomicAdd(&cnt[dst], 1);
  }
}

// Phase 1: per-block exclusive scan (in-block), block totals out.
__global__ __launch_bounds__(256) void scan1_kernel(
    const int* __restrict__ cnt, int N,
    int* __restrict__ local, int* __restrict__ blocksum) {
  int i = blockIdx.x * 256 + threadIdx.x;
  int v = (i < N) ? cnt[i] : 0;
  int lane = threadIdx.x & 63, w = threadIdx.x >> 6;
  int x = v;
#pragma unroll
  for (int off = 1; off < 64; off <<= 1) {
    int t = __shfl_up(x, off, 64);
    if (lane >= off) x += t;
  }
  __shared__ int wsum[4];
  if (lane == 63) wsum[w] = x;
  __syncthreads();
  int add = 0;
#pragma unroll
  for (int k = 0; k < 4; ++k) add += (k < w) ? wsum[k] : 0;
  int incl = x + add;
  if (i < N) local[i] = incl - v;                       // block-local exclusive
  if (threadIdx.x == 255) blocksum[blockIdx.x] = incl;  // block total
}

// Phase 2: one block scans the (<=1024) block totals -> exclusive offsets.
__global__ __launch_bounds__(1024) void scan2_kernel(int* __restrict__ blocksum,
                                                     int nb) {
  int t = threadIdx.x;
  int v = (t < nb) ? blocksum[t] : 0;
  int lane = t & 63, w = t >> 6;
  int x = v;
#pragma unroll
  for (int off = 1; off < 64; off <<= 1) {
    int u = __shfl_up(x, off, 64);
    if (lane >= off) x += u;
  }
  __shared__ int wsum[16];
  if (lane == 63) wsum[w] = x;
  __syncthreads();
  int add = 0;
#pragma unroll
  for (int k = 0; k < 16; ++k) add += (k < w) ? wsum[k] : 0;
  int incl = x + add;
  if (t < nb) blocksum[t] = incl - v;  // exclusive block offset
}

// Phase 3: add block offsets, produce row_start + cursor.
__global__ __launch_bounds__(256) void scan3_kernel(
    const int* __restrict__ local, const int* __restrict__ blockoff, int N,
    int Etot, int* __restrict__ row_start, int* __restrict__ cursor) {
  int i = blockIdx.x * 256 + threadIdx.x;
  if (i < N) {
    int r = local[i] + blockoff[blockIdx.x];
    row_start[i] = r;
    cursor[i] = r;
  }
  if (i == 0) row_start[N] = Etot;
}

__global__ void scatter_kernel(const int* __restrict__ ei, int E, int Etot,
                               int* __restrict__ cursor, int* __restrict__ esrc) {
  int i = blockIdx.x * blockDim.x + threadIdx.x;
  int stride = gridDim.x * blockDim.x;
  for (; i < Etot; i += stride) {
    int src, dst;
    if (i < E) { src = ei[i]; dst = ei[E + i]; }
    else       { src = i - E; dst = i - E; }
    int pos = atomicAdd(&cursor[dst], 1);
    esrc[pos] = src;
  }
}

// ---------------- GEMM (x @ W) + attention logits ----------------
// Grid-stride waves; each wave holds its W column (64 floats) in VGPRs.
// h[n][lane] = sum_k x[n][k] * W[k][lane]; x[n][k] via __shfl broadcast.

template <int HEADS>
__global__ __launch_bounds__(256) void gemm_alpha_kernel(
    const float* __restrict__ X, const float* __restrict__ W,
    const float* __restrict__ a_s, const float* __restrict__ a_d, int N,
    float* __restrict__ H, float* __restrict__ AS, float* __restrict__ AD) {
  int lane = threadIdx.x & 63;
  int gwave = (blockIdx.x * 256 + threadIdx.x) >> 6;
  int nwaves = gridDim.x * 4;

  float w[FDIM];
#pragma unroll
  for (int k = 0; k < FDIM; ++k) w[k] = W[k * FDIM + lane];
  float as_l = a_s[lane];
  float ad_l = a_d[lane];
  constexpr int G = 64 / HEADS;

  for (int n = gwave; n < N; n += nwaves) {
    float xr = X[(size_t)n * FDIM + lane];
    float acc = 0.f;
#pragma unroll
    for (int k = 0; k < FDIM; ++k)
      acc = fmaf(__shfl(xr, k, 64), w[k], acc);
    H[(size_t)n * FDIM + lane] = acc;

    float ts = acc * as_l;
    float td = acc * ad_l;
#pragma unroll
    for (int off = 1; off < G; off <<= 1) {
      ts += __shfl_xor(ts, off, 64);
      td += __shfl_xor(td, off, 64);
    }
    if ((lane & (G - 1)) == 0) {
      int head = lane / G;
      AS[(size_t)n * HEADS + head] = ts;
      AD[(size_t)n * HEADS + head] = td;
    }
  }
}

// ---------------- online-softmax aggregation ----------------
// One wave per destination node; lane = output channel; head = lane/(64/HEADS).
// Single pass: running max m, rescaled denom/acc.
// FINAL=false: fuse +bias, ELU.  FINAL=true: fuse +bias, row L2-normalize.

template <int HEADS, bool FINAL>
__global__ __launch_bounds__(256) void aggregate_kernel(
    const int* __restrict__ row_start, const int* __restrict__ esrc,
    const float* __restrict__ H, const float* __restrict__ AS,
    const float* __restrict__ AD, const float* __restrict__ bias, int N,
    float* __restrict__ OUT) {
  int lane = threadIdx.x & 63;
  int wid = threadIdx.x >> 6;
  int n = blockIdx.x * 4 + wid;
  if (n >= N) return;

  constexpr int G = 64 / HEADS;
  int head = lane / G;

  int rs = row_start[n];
  int re = row_start[n + 1];
  float ad = AD[(size_t)n * HEADS + head];

  float m = -1e30f, denom = 0.f, acc = 0.f;
  for (int i = rs; i < re; ++i) {
    int s = esrc[i];
    float e = AS[(size_t)s * HEADS + head] + ad;
    e = e > 0.f ? e : 0.2f * e;
    float hv = H[(size_t)s * FDIM + lane];
    float mn = fmaxf(m, e);
    float sc = __expf(m - mn);   // 0 on first iter (m=-1e30), 1 when no new max
    float wg = __expf(e - mn);
    denom = fmaf(denom, sc, wg);
    acc = fmaf(acc, sc, wg * hv);
    m = mn;
  }

  float v = acc / (denom + 1e-16f) + bias[lane];
  if (FINAL) {
    float ss = v * v;
#pragma unroll
    for (int off = 1; off < 64; off <<= 1) ss += __shfl_xor(ss, off, 64);
    float norm = fmaxf(sqrtf(ss), 1e-12f);
    OUT[(size_t)n * FDIM + lane] = v / norm;
  } else {
    OUT[(size_t)n * FDIM + lane] = v > 0.f ? v : expm1f(v);
  }
}

// ---------------- launch ----------------

extern "C" void kernel_launch(void* const* d_in, const int* in_sizes, int n_in,
                              void* d_out, int out_size, void* d_ws,
                              size_t ws_size, hipStream_t stream) {
  const int* ei = (const int*)d_in[0];          // [2, E]
  const float* emb = (const float*)d_in[1];     // [N, 64]
  const float* W1 = (const float*)d_in[2];
  const float* as1 = (const float*)d_in[3];
  const float* ad1 = (const float*)d_in[4];
  const float* b1 = (const float*)d_in[5];
  const float* W2 = (const float*)d_in[6];
  const float* as2 = (const float*)d_in[7];
  const float* ad2 = (const float*)d_in[8];
  const float* b2 = (const float*)d_in[9];
  float* out = (float*)d_out;

  int E = in_sizes[0] / 2;
  int N = in_sizes[1] / FDIM;
  int Etot = E + N;
  int nb = (N + 255) / 256;  // scan blocks (<=1024 supported by scan2)

  char* ws = (char*)d_ws;
  size_t off = 0;
  auto alloc = [&](size_t bytes) -> void* {
    void* p = ws + off;
    off += (bytes + 255) & ~(size_t)255;
    return p;
  };
  int* cnt = (int*)alloc((size_t)N * sizeof(int));
  int* local = (int*)alloc((size_t)N * sizeof(int));
  int* blocksum = (int*)alloc((size_t)nb * sizeof(int));
  int* row_start = (int*)alloc((size_t)(N + 1) * sizeof(int));
  int* cursor = (int*)alloc((size_t)N * sizeof(int));
  int* esrc = (int*)alloc((size_t)Etot * sizeof(int));
  float* hbuf = (float*)alloc((size_t)N * FDIM * sizeof(float));
  float* xbuf = (float*)alloc((size_t)N * FDIM * sizeof(float));
  float* AS = (float*)alloc((size_t)N * 4 * sizeof(float));
  float* AD = (float*)alloc((size_t)N * 4 * sizeof(float));

  hipMemsetAsync(cnt, 0, (size_t)N * sizeof(int), stream);
  count_kernel<<<1024, 256, 0, stream>>>(ei, E, Etot, cnt);
  scan1_kernel<<<nb, 256, 0, stream>>>(cnt, N, local, blocksum);
  scan2_kernel<<<1, 1024, 0, stream>>>(blocksum, nb);
  scan3_kernel<<<nb, 256, 0, stream>>>(local, blocksum, N, Etot, row_start, cursor);
  scatter_kernel<<<1024, 256, 0, stream>>>(ei, E, Etot, cursor, esrc);

  int gb = (N + 3) / 4;
  // Layer 1: GATConv(64 -> 16, heads=4, concat) + bias + ELU
  gemm_alpha_kernel<4><<<1024, 256, 0, stream>>>(emb, W1, as1, ad1, N, hbuf, AS, AD);
  aggregate_kernel<4, false><<<gb, 256, 0, stream>>>(row_start, esrc, hbuf, AS, AD, b1, N, xbuf);
  // Layer 2: GATConv(64 -> 64, heads=1) + bias + L2 normalize
  gemm_alpha_kernel<1><<<1024, 256, 0, stream>>>(xbuf, W2, as2, ad2, N, hbuf, AS, AD);
  aggregate_kernel<1, true><<<gb, 256, 0, stream>>>(row_start, esrc, hbuf, AS, AD, b2, N, out);
}

// Round 3
// 449.619 us; speedup vs baseline: 2.0128x; 1.1887x over previous
//
#include <hip/hip_runtime.h>
#include <hip/hip_fp16.h>
#include <math.h>

// GAT 2-layer forward on MI355X.
// CSR build (count / 3-phase parallel scan / scatter) once per call, then per layer:
//   gemm_alpha: h = x@W (W column in VGPRs, shfl-broadcast x), h stored FP16
//   aggregate:  wave = 2 dst nodes, lane = channel-pair (__half2 gathers),
//               online-softmax weighted sum, fused epilogue.

constexpr int FDIM = 64;

// ---------------- CSR build ----------------

__global__ void count_kernel(const int* __restrict__ ei, int E, int Etot,
                             int* __restrict__ cnt) {
  int i = blockIdx.x * blockDim.x + threadIdx.x;
  int stride = gridDim.x * blockDim.x;
  for (; i < Etot; i += stride) {
    int dst = (i < E) ? ei[E + i] : (i - E);   // self-loops appended
    atomicAdd(&cnt[dst], 1);
  }
}

// Phase 1: per-block exclusive scan (in-block), block totals out.
__global__ __launch_bounds__(256) void scan1_kernel(
    const int* __restrict__ cnt, int N,
    int* __restrict__ local, int* __restrict__ blocksum) {
  int i = blockIdx.x * 256 + threadIdx.x;
  int v = (i < N) ? cnt[i] : 0;
  int lane = threadIdx.x & 63, w = threadIdx.x >> 6;
  int x = v;
#pragma unroll
  for (int off = 1; off < 64; off <<= 1) {
    int t = __shfl_up(x, off, 64);
    if (lane >= off) x += t;
  }
  __shared__ int wsum[4];
  if (lane == 63) wsum[w] = x;
  __syncthreads();
  int add = 0;
#pragma unroll
  for (int k = 0; k < 4; ++k) add += (k < w) ? wsum[k] : 0;
  int incl = x + add;
  if (i < N) local[i] = incl - v;                       // block-local exclusive
  if (threadIdx.x == 255) blocksum[blockIdx.x] = incl;  // block total
}

// Phase 2: one block scans the (<=1024) block totals -> exclusive offsets.
__global__ __launch_bounds__(1024) void scan2_kernel(int* __restrict__ blocksum,
                                                     int nb) {
  int t = threadIdx.x;
  int v = (t < nb) ? blocksum[t] : 0;
  int lane = t & 63, w = t >> 6;
  int x = v;
#pragma unroll
  for (int off = 1; off < 64; off <<= 1) {
    int u = __shfl_up(x, off, 64);
    if (lane >= off) x += u;
  }
  __shared__ int wsum[16];
  if (lane == 63) wsum[w] = x;
  __syncthreads();
  int add = 0;
#pragma unroll
  for (int k = 0; k < 16; ++k) add += (k < w) ? wsum[k] : 0;
  int incl = x + add;
  if (t < nb) blocksum[t] = incl - v;  // exclusive block offset
}

// Phase 3: add block offsets, produce row_start + cursor.
__global__ __launch_bounds__(256) void scan3_kernel(
    const int* __restrict__ local, const int* __restrict__ blockoff, int N,
    int Etot, int* __restrict__ row_start, int* __restrict__ cursor) {
  int i = blockIdx.x * 256 + threadIdx.x;
  if (i < N) {
    int r = local[i] + blockoff[blockIdx.x];
    row_start[i] = r;
    cursor[i] = r;
  }
  if (i == 0) row_start[N] = Etot;
}

__global__ void scatter_kernel(const int* __restrict__ ei, int E, int Etot,
                               int* __restrict__ cursor, int* __restrict__ esrc) {
  int i = blockIdx.x * blockDim.x + threadIdx.x;
  int stride = gridDim.x * blockDim.x;
  for (; i < Etot; i += stride) {
    int src, dst;
    if (i < E) { src = ei[i]; dst = ei[E + i]; }
    else       { src = i - E; dst = i - E; }
    int pos = atomicAdd(&cursor[dst], 1);
    esrc[pos] = src;
  }
}

// ---------------- GEMM (x @ W) + attention logits ----------------
// Grid-stride waves; each wave holds its W column (64 floats) in VGPRs.
// h stored FP16 (compute fp32), attention logits fp32.

template <int HEADS>
__global__ __launch_bounds__(256) void gemm_alpha_kernel(
    const float* __restrict__ X, const float* __restrict__ W,
    const float* __restrict__ a_s, const float* __restrict__ a_d, int N,
    __half* __restrict__ H, float* __restrict__ AS, float* __restrict__ AD) {
  int lane = threadIdx.x & 63;
  int gwave = (blockIdx.x * 256 + threadIdx.x) >> 6;
  int nwaves = gridDim.x * 4;

  float w[FDIM];
#pragma unroll
  for (int k = 0; k < FDIM; ++k) w[k] = W[k * FDIM + lane];
  float as_l = a_s[lane];
  float ad_l = a_d[lane];
  constexpr int G = 64 / HEADS;

  for (int n = gwave; n < N; n += nwaves) {
    float xr = X[(size_t)n * FDIM + lane];
    float acc = 0.f;
#pragma unroll
    for (int k = 0; k < FDIM; ++k)
      acc = fmaf(__shfl(xr, k, 64), w[k], acc);
    H[(size_t)n * FDIM + lane] = __float2half(acc);

    float ts = acc * as_l;
    float td = acc * ad_l;
#pragma unroll
    for (int off = 1; off < G; off <<= 1) {
      ts += __shfl_xor(ts, off, 64);
      td += __shfl_xor(td, off, 64);
    }
    if ((lane & (G - 1)) == 0) {
      int head = lane / G;
      AS[(size_t)n * HEADS + head] = ts;
      AD[(size_t)n * HEADS + head] = td;
    }
  }
}

// ---------------- online-softmax aggregation ----------------
// Wave = 2 dst nodes (lanes 0-31 node A, lanes 32-63 node B).
// Lane owns channel pair (2c, 2c+1), gathered as __half2; accumulate fp32.
// FINAL=false: fuse +bias, ELU.  FINAL=true: fuse +bias, row L2-normalize.

template <int HEADS, bool FINAL>
__global__ __launch_bounds__(256) void aggregate_kernel(
    const int* __restrict__ row_start, const int* __restrict__ esrc,
    const __half* __restrict__ H, const float* __restrict__ AS,
    const float* __restrict__ AD, const float* __restrict__ bias, int N,
    float* __restrict__ OUT) {
  int t = threadIdx.x;
  int wid = t >> 6;
  int half = (t >> 5) & 1;
  int ll = t & 31;                       // lane within half-wave
  int n = blockIdx.x * 8 + wid * 2 + half;

  constexpr int G = 64 / HEADS;          // channels per head
  int head = (2 * ll) / G;               // both channels in same head (G>=2)

  int rs = 0, re = 0;
  float ad = 0.f;
  if (n < N) {
    rs = row_start[n];
    re = row_start[n + 1];
    ad = AD[(size_t)n * HEADS + head];
  }
  int deg = re - rs;
  int degO = __shfl_xor(deg, 32, 64);    // other half's degree (uniform there)
  int degmax = max(deg, degO);

  const __half2* H2 = reinterpret_cast<const __half2*>(H);

  float m = -1e30f, denom = 0.f, ax = 0.f, ay = 0.f;
  for (int i = 0; i < degmax; ++i) {
    if (i < deg) {
      int s = esrc[rs + i];
      float e = AS[(size_t)s * HEADS + head] + ad;
      e = e > 0.f ? e : 0.2f * e;
      float2 hf = __half22float2(H2[(size_t)s * 32 + ll]);
      float mn = fmaxf(m, e);
      float sc = __expf(m - mn);
      float wg = __expf(e - mn);
      denom = fmaf(denom, sc, wg);
      ax = fmaf(ax, sc, wg * hf.x);
      ay = fmaf(ay, sc, wg * hf.y);
      m = mn;
    }
  }

  if (n >= N) return;

  float2 b2 = reinterpret_cast<const float2*>(bias)[ll];
  float inv = 1.f / (denom + 1e-16f);
  float vx = ax * inv + b2.x;
  float vy = ay * inv + b2.y;
  float2* OUT2 = reinterpret_cast<float2*>(OUT);
  if (FINAL) {
    float ss = vx * vx + vy * vy;
#pragma unroll
    for (int off = 1; off < 32; off <<= 1) ss += __shfl_xor(ss, off, 32);
    float rn = 1.f / fmaxf(sqrtf(ss), 1e-12f);
    OUT2[(size_t)n * 32 + ll] = make_float2(vx * rn, vy * rn);
  } else {
    vx = vx > 0.f ? vx : expm1f(vx);
    vy = vy > 0.f ? vy : expm1f(vy);
    OUT2[(size_t)n * 32 + ll] = make_float2(vx, vy);
  }
}

// ---------------- launch ----------------

extern "C" void kernel_launch(void* const* d_in, const int* in_sizes, int n_in,
                              void* d_out, int out_size, void* d_ws,
                              size_t ws_size, hipStream_t stream) {
  const int* ei = (const int*)d_in[0];          // [2, E]
  const float* emb = (const float*)d_in[1];     // [N, 64]
  const float* W1 = (const float*)d_in[2];
  const float* as1 = (const float*)d_in[3];
  const float* ad1 = (const float*)d_in[4];
  const float* b1 = (const float*)d_in[5];
  const float* W2 = (const float*)d_in[6];
  const float* as2 = (const float*)d_in[7];
  const float* ad2 = (const float*)d_in[8];
  const float* b2 = (const float*)d_in[9];
  float* out = (float*)d_out;

  int E = in_sizes[0] / 2;
  int N = in_sizes[1] / FDIM;
  int Etot = E + N;
  int nb = (N + 255) / 256;  // scan blocks (<=1024 supported by scan2)

  char* ws = (char*)d_ws;
  size_t off = 0;
  auto alloc = [&](size_t bytes) -> void* {
    void* p = ws + off;
    off += (bytes + 255) & ~(size_t)255;
    return p;
  };
  int* cnt = (int*)alloc((size_t)N * sizeof(int));
  int* local = (int*)alloc((size_t)N * sizeof(int));
  int* blocksum = (int*)alloc((size_t)nb * sizeof(int));
  int* row_start = (int*)alloc((size_t)(N + 1) * sizeof(int));
  int* cursor = (int*)alloc((size_t)N * sizeof(int));
  int* esrc = (int*)alloc((size_t)Etot * sizeof(int));
  __half* hbuf = (__half*)alloc((size_t)N * FDIM * sizeof(__half));
  float* xbuf = (float*)alloc((size_t)N * FDIM * sizeof(float));
  float* AS = (float*)alloc((size_t)N * 4 * sizeof(float));
  float* AD = (float*)alloc((size_t)N * 4 * sizeof(float));

  hipMemsetAsync(cnt, 0, (size_t)N * sizeof(int), stream);
  count_kernel<<<1024, 256, 0, stream>>>(ei, E, Etot, cnt);
  scan1_kernel<<<nb, 256, 0, stream>>>(cnt, N, local, blocksum);
  scan2_kernel<<<1, 1024, 0, stream>>>(blocksum, nb);
  scan3_kernel<<<nb, 256, 0, stream>>>(local, blocksum, N, Etot, row_start, cursor);
  scatter_kernel<<<1024, 256, 0, stream>>>(ei, E, Etot, cursor, esrc);

  int ga = (N + 7) / 8;  // aggregate: 8 nodes per block (4 waves x 2)
  // Layer 1: GATConv(64 -> 16, heads=4, concat) + bias + ELU
  gemm_alpha_kernel<4><<<1024, 256, 0, stream>>>(emb, W1, as1, ad1, N, hbuf, AS, AD);
  aggregate_kernel<4, false><<<ga, 256, 0, stream>>>(row_start, esrc, hbuf, AS, AD, b1, N, xbuf);
  // Layer 2: GATConv(64 -> 64, heads=1) + bias + L2 normalize
  gemm_alpha_kernel<1><<<1024, 256, 0, stream>>>(xbuf, W2, as2, ad2, N, hbuf, AS, AD);
  aggregate_kernel<1, true><<<ga, 256, 0, stream>>>(row_start, esrc, hbuf, AS, AD, b2, N, out);
}

// Round 4
// 342.920 us; speedup vs baseline: 2.6391x; 1.3111x over previous
//
#include <hip/hip_runtime.h>
#include <hip/hip_fp16.h>
#include <math.h>

// GAT 2-layer forward on MI355X.
// CSR build (count / 3-phase parallel scan / scatter) once per call, then per layer:
//   gemm_alpha: h = x@W; x-row via SCALAR loads (wave-uniform), 8 indep fma chains,
//               h stored FP16; attention logits fp32.
//   aggregate:  wave = 2 dst nodes, lane = channel-pair (__half2 gathers),
//               online-softmax weighted sum, fused epilogue.

constexpr int FDIM = 64;

// ---------------- CSR build ----------------

__global__ void count_kernel(const int* __restrict__ ei, int E, int Etot,
                             int* __restrict__ cnt) {
  int i = blockIdx.x * blockDim.x + threadIdx.x;
  int stride = gridDim.x * blockDim.x;
  for (; i < Etot; i += stride) {
    int dst = (i < E) ? ei[E + i] : (i - E);   // self-loops appended
    atomicAdd(&cnt[dst], 1);
  }
}

// Phase 1: per-block exclusive scan (in-block), block totals out.
__global__ __launch_bounds__(256) void scan1_kernel(
    const int* __restrict__ cnt, int N,
    int* __restrict__ local, int* __restrict__ blocksum) {
  int i = blockIdx.x * 256 + threadIdx.x;
  int v = (i < N) ? cnt[i] : 0;
  int lane = threadIdx.x & 63, w = threadIdx.x >> 6;
  int x = v;
#pragma unroll
  for (int off = 1; off < 64; off <<= 1) {
    int t = __shfl_up(x, off, 64);
    if (lane >= off) x += t;
  }
  __shared__ int wsum[4];
  if (lane == 63) wsum[w] = x;
  __syncthreads();
  int add = 0;
#pragma unroll
  for (int k = 0; k < 4; ++k) add += (k < w) ? wsum[k] : 0;
  int incl = x + add;
  if (i < N) local[i] = incl - v;                       // block-local exclusive
  if (threadIdx.x == 255) blocksum[blockIdx.x] = incl;  // block total
}

// Phase 2: one block scans the (<=1024) block totals -> exclusive offsets.
__global__ __launch_bounds__(1024) void scan2_kernel(int* __restrict__ blocksum,
                                                     int nb) {
  int t = threadIdx.x;
  int v = (t < nb) ? blocksum[t] : 0;
  int lane = t & 63, w = t >> 6;
  int x = v;
#pragma unroll
  for (int off = 1; off < 64; off <<= 1) {
    int u = __shfl_up(x, off, 64);
    if (lane >= off) x += u;
  }
  __shared__ int wsum[16];
  if (lane == 63) wsum[w] = x;
  __syncthreads();
  int add = 0;
#pragma unroll
  for (int k = 0; k < 16; ++k) add += (k < w) ? wsum[k] : 0;
  int incl = x + add;
  if (t < nb) blocksum[t] = incl - v;  // exclusive block offset
}

// Phase 3: add block offsets, produce row_start + cursor.
__global__ __launch_bounds__(256) void scan3_kernel(
    const int* __restrict__ local, const int* __restrict__ blockoff, int N,
    int Etot, int* __restrict__ row_start, int* __restrict__ cursor) {
  int i = blockIdx.x * 256 + threadIdx.x;
  if (i < N) {
    int r = local[i] + blockoff[blockIdx.x];
    row_start[i] = r;
    cursor[i] = r;
  }
  if (i == 0) row_start[N] = Etot;
}

__global__ void scatter_kernel(const int* __restrict__ ei, int E, int Etot,
                               int* __restrict__ cursor, int* __restrict__ esrc) {
  int i = blockIdx.x * blockDim.x + threadIdx.x;
  int stride = gridDim.x * blockDim.x;
  for (; i < Etot; i += stride) {
    int src, dst;
    if (i < E) { src = ei[i]; dst = ei[E + i]; }
    else       { src = i - E; dst = i - E; }
    int pos = atomicAdd(&cursor[dst], 1);
    esrc[pos] = src;
  }
}

// ---------------- GEMM (x @ W) + attention logits ----------------
// Grid-stride waves; W column (64 floats) in VGPRs. Row index forced scalar
// (readfirstlane) so x-row elements come from s_load (scalar pipe), not
// ds_bpermute. 2 rows/iter x 4 accumulators = 8 independent fma chains.

template <int HEADS>
__global__ __launch_bounds__(256) void gemm_alpha_kernel(
    const float* __restrict__ X, const float* __restrict__ W,
    const float* __restrict__ a_s, const float* __restrict__ a_d, int N,
    __half* __restrict__ H, float* __restrict__ AS, float* __restrict__ AD) {
  int lane = threadIdx.x & 63;
  int gwave = (blockIdx.x * 256 + threadIdx.x) >> 6;
  int nwaves = gridDim.x * 4;

  float w[FDIM];
#pragma unroll
  for (int k = 0; k < FDIM; ++k) w[k] = W[k * FDIM + lane];
  float as_l = a_s[lane];
  float ad_l = a_d[lane];
  constexpr int G = 64 / HEADS;

  for (int n = gwave * 2; n < N; n += nwaves * 2) {
    int nu = __builtin_amdgcn_readfirstlane(n);
    const float* xa = X + (size_t)nu * FDIM;
    bool twob = (nu + 1) < N;
    const float* xb = twob ? (xa + FDIM) : xa;

    float a0 = 0.f, a1 = 0.f, a2 = 0.f, a3 = 0.f;
    float c0 = 0.f, c1 = 0.f, c2 = 0.f, c3 = 0.f;
#pragma unroll
    for (int k = 0; k < FDIM; k += 4) {
      a0 = fmaf(xa[k + 0], w[k + 0], a0);
      a1 = fmaf(xa[k + 1], w[k + 1], a1);
      a2 = fmaf(xa[k + 2], w[k + 2], a2);
      a3 = fmaf(xa[k + 3], w[k + 3], a3);
      c0 = fmaf(xb[k + 0], w[k + 0], c0);
      c1 = fmaf(xb[k + 1], w[k + 1], c1);
      c2 = fmaf(xb[k + 2], w[k + 2], c2);
      c3 = fmaf(xb[k + 3], w[k + 3], c3);
    }
    float ha = (a0 + a1) + (a2 + a3);
    float hb = (c0 + c1) + (c2 + c3);

    H[(size_t)nu * FDIM + lane] = __float2half(ha);
    if (twob) H[(size_t)(nu + 1) * FDIM + lane] = __float2half(hb);

    float tsa = ha * as_l, tda = ha * ad_l;
    float tsb = hb * as_l, tdb = hb * ad_l;
#pragma unroll
    for (int off = 1; off < G; off <<= 1) {
      tsa += __shfl_xor(tsa, off, 64);
      tda += __shfl_xor(tda, off, 64);
      tsb += __shfl_xor(tsb, off, 64);
      tdb += __shfl_xor(tdb, off, 64);
    }
    if ((lane & (G - 1)) == 0) {
      int head = lane / G;
      AS[(size_t)nu * HEADS + head] = tsa;
      AD[(size_t)nu * HEADS + head] = tda;
      if (twob) {
        AS[(size_t)(nu + 1) * HEADS + head] = tsb;
        AD[(size_t)(nu + 1) * HEADS + head] = tdb;
      }
    }
  }
}

// ---------------- online-softmax aggregation ----------------
// Wave = 2 dst nodes (lanes 0-31 node A, lanes 32-63 node B).
// Lane owns channel pair (2c, 2c+1), gathered as __half2; accumulate fp32.
// FINAL=false: fuse +bias, ELU.  FINAL=true: fuse +bias, row L2-normalize.

template <int HEADS, bool FINAL>
__global__ __launch_bounds__(256) void aggregate_kernel(
    const int* __restrict__ row_start, const int* __restrict__ esrc,
    const __half* __restrict__ H, const float* __restrict__ AS,
    const float* __restrict__ AD, const float* __restrict__ bias, int N,
    float* __restrict__ OUT) {
  int t = threadIdx.x;
  int wid = t >> 6;
  int half = (t >> 5) & 1;
  int ll = t & 31;                       // lane within half-wave
  int n = blockIdx.x * 8 + wid * 2 + half;

  constexpr int G = 64 / HEADS;          // channels per head
  int head = (2 * ll) / G;               // both channels in same head (G>=2)

  int rs = 0, re = 0;
  float ad = 0.f;
  if (n < N) {
    rs = row_start[n];
    re = row_start[n + 1];
    ad = AD[(size_t)n * HEADS + head];
  }
  int deg = re - rs;
  int degO = __shfl_xor(deg, 32, 64);    // other half's degree (uniform there)
  int degmax = max(deg, degO);

  const __half2* H2 = reinterpret_cast<const __half2*>(H);

  float m = -1e30f, denom = 0.f, ax = 0.f, ay = 0.f;
  for (int i = 0; i < degmax; ++i) {
    if (i < deg) {
      int s = esrc[rs + i];
      float e = AS[(size_t)s * HEADS + head] + ad;
      e = e > 0.f ? e : 0.2f * e;
      float2 hf = __half22float2(H2[(size_t)s * 32 + ll]);
      float mn = fmaxf(m, e);
      float sc = __expf(m - mn);
      float wg = __expf(e - mn);
      denom = fmaf(denom, sc, wg);
      ax = fmaf(ax, sc, wg * hf.x);
      ay = fmaf(ay, sc, wg * hf.y);
      m = mn;
    }
  }

  if (n >= N) return;

  float2 b2 = reinterpret_cast<const float2*>(bias)[ll];
  float inv = 1.f / (denom + 1e-16f);
  float vx = ax * inv + b2.x;
  float vy = ay * inv + b2.y;
  float2* OUT2 = reinterpret_cast<float2*>(OUT);
  if (FINAL) {
    float ss = vx * vx + vy * vy;
#pragma unroll
    for (int off = 1; off < 32; off <<= 1) ss += __shfl_xor(ss, off, 32);
    float rn = 1.f / fmaxf(sqrtf(ss), 1e-12f);
    OUT2[(size_t)n * 32 + ll] = make_float2(vx * rn, vy * rn);
  } else {
    vx = vx > 0.f ? vx : expm1f(vx);
    vy = vy > 0.f ? vy : expm1f(vy);
    OUT2[(size_t)n * 32 + ll] = make_float2(vx, vy);
  }
}

// ---------------- launch ----------------

extern "C" void kernel_launch(void* const* d_in, const int* in_sizes, int n_in,
                              void* d_out, int out_size, void* d_ws,
                              size_t ws_size, hipStream_t stream) {
  const int* ei = (const int*)d_in[0];          // [2, E]
  const float* emb = (const float*)d_in[1];     // [N, 64]
  const float* W1 = (const float*)d_in[2];
  const float* as1 = (const float*)d_in[3];
  const float* ad1 = (const float*)d_in[4];
  const float* b1 = (const float*)d_in[5];
  const float* W2 = (const float*)d_in[6];
  const float* as2 = (const float*)d_in[7];
  const float* ad2 = (const float*)d_in[8];
  const float* b2 = (const float*)d_in[9];
  float* out = (float*)d_out;

  int E = in_sizes[0] / 2;
  int N = in_sizes[1] / FDIM;
  int Etot = E + N;
  int nb = (N + 255) / 256;  // scan blocks (<=1024 supported by scan2)

  char* ws = (char*)d_ws;
  size_t off = 0;
  auto alloc = [&](size_t bytes) -> void* {
    void* p = ws + off;
    off += (bytes + 255) & ~(size_t)255;
    return p;
  };
  int* cnt = (int*)alloc((size_t)N * sizeof(int));
  int* local = (int*)alloc((size_t)N * sizeof(int));
  int* blocksum = (int*)alloc((size_t)nb * sizeof(int));
  int* row_start = (int*)alloc((size_t)(N + 1) * sizeof(int));
  int* cursor = (int*)alloc((size_t)N * sizeof(int));
  int* esrc = (int*)alloc((size_t)Etot * sizeof(int));
  __half* hbuf = (__half*)alloc((size_t)N * FDIM * sizeof(__half));
  float* xbuf = (float*)alloc((size_t)N * FDIM * sizeof(float));
  float* AS = (float*)alloc((size_t)N * 4 * sizeof(float));
  float* AD = (float*)alloc((size_t)N * 4 * sizeof(float));

  hipMemsetAsync(cnt, 0, (size_t)N * sizeof(int), stream);
  count_kernel<<<1024, 256, 0, stream>>>(ei, E, Etot, cnt);
  scan1_kernel<<<nb, 256, 0, stream>>>(cnt, N, local, blocksum);
  scan2_kernel<<<1, 1024, 0, stream>>>(blocksum, nb);
  scan3_kernel<<<nb, 256, 0, stream>>>(local, blocksum, N, Etot, row_start, cursor);
  scatter_kernel<<<1024, 256, 0, stream>>>(ei, E, Etot, cursor, esrc);

  int ga = (N + 7) / 8;  // aggregate: 8 nodes per block (4 waves x 2)
  // Layer 1: GATConv(64 -> 16, heads=4, concat) + bias + ELU
  gemm_alpha_kernel<4><<<2048, 256, 0, stream>>>(emb, W1, as1, ad1, N, hbuf, AS, AD);
  aggregate_kernel<4, false><<<ga, 256, 0, stream>>>(row_start, esrc, hbuf, AS, AD, b1, N, xbuf);
  // Layer 2: GATConv(64 -> 64, heads=1) + bias + L2 normalize
  gemm_alpha_kernel<1><<<2048, 256, 0, stream>>>(xbuf, W2, as2, ad2, N, hbuf, AS, AD);
  aggregate_kernel<1, true><<<ga, 256, 0, stream>>>(row_start, esrc, hbuf, AS, AD, b2, N, out);
}